// Round 1
// baseline (291.801 us; speedup 1.0000x reference)
//
#include <hip/hip_runtime.h>

// GridSample (bilinear, zeros padding, align_corners=True, pixel-offset grid).
// x:    [N=8, C=64, H=256, W=256] f32
// grid: [N=8, Ho=256, Wo=256, 2]  f32  (dx, dy) pixel offsets
// out:  [N, C, Ho, Wo] f32
//
// v4: LDS row-window staging. v3 was TA-bound: 16 scattered dwordx2 gathers
// per wave at ~47 cyc each (each wave64 gather spans ~4-6 image rows => ~20-30
// cache lines). Since iy = ho + dy (dy ~ N(0,1)), one (n,ho) block only needs
// a ~9-10-row contiguous window of x. So: block-reduce [ymin,ymax], stage the
// window per channel into LDS via linear global_load_lds (1 instr per 1KB row
// per wave, fully coalesced), gather via ds_read2_b32 (~6 cyc). Double-buffer
// across channels. Per-lane global fallback covers rows outside the clipped
// window (RMAX), so correctness is data-independent.
// v2's XCD swizzle kept (per-XCD working set ~2MB < 4MiB L2).

#define N_ 8
#define C_ 64
#define H_ 256
#define W_ 256
#define HO_ 256
#define WO_ 256
#define CCH 8          // channels per block
#define NCC (C_ / CCH) // 8 channel chunks
#define RMAX 12        // max staged rows per buffer (typ. window ~9-10)
#define LDSW 260       // LDS row pitch in floats: 256 + 4 pad (bank spread, 16B-aligned)

__global__ __launch_bounds__(256) void gridsample_kernel(
    const float* __restrict__ x,
    const float2* __restrict__ grid2,
    float* __restrict__ out)
{
    __shared__ __attribute__((aligned(16))) float sm[2][RMAX * LDSW]; // 24960 B
    __shared__ int swin[8];   // [0..3] per-wave min, [4..7] per-wave max

    // XCD k (= blockIdx % 8) gets planes k*8..k*8+7 (plane = (n, c-chunk)).
    const int b     = blockIdx.x;
    const int xcd   = b & 7;
    const int idx   = b >> 3;                 // 0..2047
    const int plane = xcd * (NCC * N_ / 8) + (idx >> 8);
    const int ho    = idx & 255;
    const int n     = plane >> 3;
    const int cc    = plane & 7;
    const int wo    = threadIdx.x;
    const int ln    = threadIdx.x & 63;
    const int wv    = threadIdx.x >> 6;       // wave id 0..3

    const int sp = (n * HO_ + ho) * WO_ + wo;
    const float2 g = grid2[sp];

    // Replicate the reference fp32 chain exactly (same as v3).
    const float absx = g.x + (float)wo;
    const float absy = g.y + (float)ho;
    const float normx = absx * 2.0f / (float)(W_ - 1) - 1.0f;
    const float normy = absy * 2.0f / (float)(H_ - 1) - 1.0f;
    const float ix = (normx + 1.0f) * 0.5f * (float)(W_ - 1);
    const float iy = (normy + 1.0f) * 0.5f * (float)(H_ - 1);

    const float x0f = floorf(ix);
    const float y0f = floorf(iy);
    const float x1f = x0f + 1.0f;
    const float y1f = y0f + 1.0f;

    const float wx1 = ix - x0f, wx0 = 1.0f - wx1;
    const float wy1 = iy - y0f, wy0 = 1.0f - wy1;

    const float hx0 = ((x0f >= 0.0f) && (x0f <= (float)(W_ - 1))) ? wx0 : 0.0f;
    const float hx1 = ((x1f >= 0.0f) && (x1f <= (float)(W_ - 1))) ? wx1 : 0.0f;
    const float ey0 = ((y0f >= 0.0f) && (y0f <= (float)(H_ - 1))) ? wy0 : 0.0f;
    const float ey1 = ((y1f >= 0.0f) && (y1f <= (float)(H_ - 1))) ? wy1 : 0.0f;

    const int xlo = (int)fminf(fmaxf(x0f, 0.0f), (float)(W_ - 2));
    const bool hi = (x0f >= (float)(W_ - 1));   // corner0 landed on pair.y
    const bool lo = (x0f <= -1.0f);             // corner1 landed on pair.x
    const float A = (hi ? 0.0f : hx0) + (lo ? hx1 : 0.0f);  // weight of pair.x
    const float B = (hi ? hx0 : 0.0f) + (lo ? 0.0f : hx1);  // weight of pair.y

    const float W00 = A * ey0, W01 = B * ey0;
    const float W10 = A * ey1, W11 = B * ey1;

    const int yr0 = min(max((int)y0f, 0), H_ - 1);
    const int yr1 = min(max((int)y1f, 0), H_ - 1);

    // Block-wide row window [wlo, whi] (uniform after the barrier).
    int lmin = yr0, lmax = yr1;
    #pragma unroll
    for (int m = 32; m >= 1; m >>= 1) {
        lmin = min(lmin, __shfl_xor(lmin, m));
        lmax = max(lmax, __shfl_xor(lmax, m));
    }
    if (ln == 0) { swin[wv] = lmin; swin[4 + wv] = lmax; }
    __syncthreads();
    const int wlo  = min(min(swin[0], swin[1]), min(swin[2], swin[3]));
    const int whi0 = max(max(swin[4], swin[5]), max(swin[6], swin[7]));
    const int whi  = min(whi0, wlo + RMAX - 1);   // clip to LDS budget
    const int R    = whi - wlo + 1;               // 1..RMAX rows to stage

    // Channel-invariant LDS offsets (clamped so speculative reads stay in-bounds)
    // and global fallback offsets for rows beyond the clipped window.
    const int o0 = min(yr0 - wlo, RMAX - 1) * LDSW + xlo;
    const int o1 = min(yr1 - wlo, RMAX - 1) * LDSW + xlo;
    const bool oow0 = yr0 > whi;
    const bool oow1 = yr1 > whi;
    const int r0 = yr0 * W_ + xlo;
    const int r1 = yr1 * W_ + xlo;

    const int c0 = cc * CCH;
    const float* __restrict__ xb =
        x + ((size_t)n * C_ + c0) * (H_ * W_);
    float* __restrict__ ob =
        out + (((size_t)n * C_ + c0) * HO_ + ho) * WO_ + wo;

    // Prologue: stage channel 0 into buffer 0. One global_load_lds per row per
    // wave: 64 lanes x 16B = 1024B = exactly one W=256 f32 row; LDS dest is
    // wave-uniform (r = wv mod 4), linear, 16B-aligned (LDSW*4 = 1040).
    for (int r = wv; r < R; r += 4) {
        const float* gp = xb + (size_t)(wlo + r) * W_ + ln * 4;
        __builtin_amdgcn_global_load_lds(
            (const __attribute__((address_space(1))) void*)gp,
            (__attribute__((address_space(3))) void*)&sm[0][r * LDSW],
            16, 0, 0);
    }
    __syncthreads();   // vmcnt drained by barrier => rows ready

    #pragma unroll
    for (int c = 0; c < CCH; ++c) {
        // Stage next channel into the other buffer; its vmcnt drains at the
        // barrier at the END of this iteration, overlapping with this
        // channel's gather+store. Buffer (c+1)&1 was last read in iteration
        // c-1, whose end-barrier already fenced those reads.
        if (c + 1 < CCH) {
            const float* xn = xb + (size_t)(c + 1) * (H_ * W_);
            for (int r = wv; r < R; r += 4) {
                const float* gp = xn + (size_t)(wlo + r) * W_ + ln * 4;
                __builtin_amdgcn_global_load_lds(
                    (const __attribute__((address_space(1))) void*)gp,
                    (__attribute__((address_space(3))) void*)&sm[(c + 1) & 1][r * LDSW],
                    16, 0, 0);
            }
        }

        const float* smb = sm[c & 1];
        float p00 = smb[o0];
        float p01 = smb[o0 + 1];
        float p10 = smb[o1];
        float p11 = smb[o1 + 1];

        // Rare fallback: row fell outside the clipped window (R > RMAX case).
        if (__builtin_expect(oow0, 0)) {
            const float* xc = xb + (size_t)c * (H_ * W_);
            p00 = xc[r0];
            p01 = xc[r0 + 1];
        }
        if (__builtin_expect(oow1, 0)) {
            const float* xc = xb + (size_t)c * (H_ * W_);
            p10 = xc[r1];
            p11 = xc[r1 + 1];
        }

        ob[(size_t)c * (HO_ * WO_)] =
            p00 * W00 + p01 * W01 + p10 * W10 + p11 * W11;

        if (c + 1 < CCH) __syncthreads();
    }
}

extern "C" void kernel_launch(void* const* d_in, const int* in_sizes, int n_in,
                              void* d_out, int out_size, void* d_ws, size_t ws_size,
                              hipStream_t stream) {
    const float*  x    = (const float*)d_in[0];
    const float2* grid = (const float2*)d_in[1];
    float*        out  = (float*)d_out;

    const int nblocks = N_ * NCC * HO_;   // 16384 blocks of 256 threads
    gridsample_kernel<<<nblocks, 256, 0, stream>>>(x, grid, out);
}

// Round 2
// 279.499 us; speedup vs baseline: 1.0440x; 1.0440x over previous
//
#include <hip/hip_runtime.h>

// GridSample (bilinear, zeros padding, align_corners=True, pixel-offset grid).
// x:    [N=8, C=64, H=256, W=256] f32
// grid: [N=8, Ho=256, Wo=256, 2]  f32  (dx, dy) pixel offsets
// out:  [N, C, Ho, Wo] f32
//
// v5: HB=2 output rows per block. v4 (per-ho LDS staging) was stall-bound:
// per-channel compute (~150 cyc) << staging latency (~600 cyc) and every
// __syncthreads drains vmcnt(0), so blocks spent ~50% idle at 8 barriers.
// Covering 2 ho-rows per block only grows the staged window by ~1 row but
// doubles compute per barrier, halves barriers per output, and halves
// staging traffic per output (L1-path floor 85K -> 60K cyc/CU).
// Keeps: XCD swizzle, paired-corner loads, channel double-buffer,
// per-pixel global fallback for rows beyond the clipped window.

#define N_ 8
#define C_ 64
#define H_ 256
#define W_ 256
#define HO_ 256
#define WO_ 256
#define CCH 8          // channels per block
#define NCC (C_ / CCH) // 8 channel chunks
#define HB 2           // output rows per block
#define RMAX 15        // max staged rows per buffer (typ. window ~10-11)
#define LDSW 260       // LDS row pitch in floats: 256 + 4 pad

__global__ __launch_bounds__(256) void gridsample_kernel(
    const float* __restrict__ x,
    const float2* __restrict__ grid2,
    float* __restrict__ out)
{
    __shared__ __attribute__((aligned(16))) float sm[2][RMAX * LDSW]; // 31200 B
    __shared__ int swin[8];   // [0..3] per-wave min, [4..7] per-wave max

    // XCD k (= blockIdx % 8) gets planes k*8..k*8+7 (plane = (n, c-chunk)).
    const int b     = blockIdx.x;
    const int xcd   = b & 7;
    const int idx   = b >> 3;                 // 0..1023
    const int plane = xcd * (NCC * N_ / 8) + (idx >> 7);
    const int ho2   = (idx & 127) * HB;       // first output row
    const int n     = plane >> 3;
    const int cc    = plane & 7;
    const int wo    = threadIdx.x;
    const int ln    = threadIdx.x & 63;
    const int wv    = threadIdx.x >> 6;       // wave id 0..3

    // Per-pixel state for the HB rows this thread handles.
    float W00[HB], W01[HB], W10[HB], W11[HB];
    int   o0[HB], o1[HB], r0[HB], r1[HB];
    bool  oow0[HB], oow1[HB];
    int   yr0[HB], yr1[HB];
    int   xlo[HB];

    int lmin = H_, lmax = -1;

    #pragma unroll
    for (int j = 0; j < HB; ++j) {
        const int ho = ho2 + j;
        const int sp = (n * HO_ + ho) * WO_ + wo;
        const float2 g = grid2[sp];

        // Replicate the reference fp32 chain exactly.
        const float absx = g.x + (float)wo;
        const float absy = g.y + (float)ho;
        const float normx = absx * 2.0f / (float)(W_ - 1) - 1.0f;
        const float normy = absy * 2.0f / (float)(H_ - 1) - 1.0f;
        const float ix = (normx + 1.0f) * 0.5f * (float)(W_ - 1);
        const float iy = (normy + 1.0f) * 0.5f * (float)(H_ - 1);

        const float x0f = floorf(ix);
        const float y0f = floorf(iy);
        const float x1f = x0f + 1.0f;
        const float y1f = y0f + 1.0f;

        const float wx1 = ix - x0f, wx0 = 1.0f - wx1;
        const float wy1 = iy - y0f, wy0 = 1.0f - wy1;

        const float hx0 = ((x0f >= 0.0f) && (x0f <= (float)(W_ - 1))) ? wx0 : 0.0f;
        const float hx1 = ((x1f >= 0.0f) && (x1f <= (float)(W_ - 1))) ? wx1 : 0.0f;
        const float ey0 = ((y0f >= 0.0f) && (y0f <= (float)(H_ - 1))) ? wy0 : 0.0f;
        const float ey1 = ((y1f >= 0.0f) && (y1f <= (float)(H_ - 1))) ? wy1 : 0.0f;

        xlo[j] = (int)fminf(fmaxf(x0f, 0.0f), (float)(W_ - 2));
        const bool hi = (x0f >= (float)(W_ - 1));   // corner0 landed on pair.y
        const bool lo = (x0f <= -1.0f);             // corner1 landed on pair.x
        const float A = (hi ? 0.0f : hx0) + (lo ? hx1 : 0.0f);  // weight of pair.x
        const float B = (hi ? hx0 : 0.0f) + (lo ? 0.0f : hx1);  // weight of pair.y

        W00[j] = A * ey0; W01[j] = B * ey0;
        W10[j] = A * ey1; W11[j] = B * ey1;

        yr0[j] = min(max((int)y0f, 0), H_ - 1);
        yr1[j] = min(max((int)y1f, 0), H_ - 1);
        lmin = min(lmin, yr0[j]);
        lmax = max(lmax, yr1[j]);
    }

    // Block-wide row window [wlo, whi] (uniform after the barrier).
    #pragma unroll
    for (int m = 32; m >= 1; m >>= 1) {
        lmin = min(lmin, __shfl_xor(lmin, m));
        lmax = max(lmax, __shfl_xor(lmax, m));
    }
    if (ln == 0) { swin[wv] = lmin; swin[4 + wv] = lmax; }
    __syncthreads();
    const int wlo  = min(min(swin[0], swin[1]), min(swin[2], swin[3]));
    const int whi0 = max(max(swin[4], swin[5]), max(swin[6], swin[7]));
    const int whi  = min(whi0, wlo + RMAX - 1);   // clip to LDS budget
    const int R    = whi - wlo + 1;               // 1..RMAX rows to stage

    #pragma unroll
    for (int j = 0; j < HB; ++j) {
        o0[j] = min(yr0[j] - wlo, RMAX - 1) * LDSW + xlo[j];
        o1[j] = min(yr1[j] - wlo, RMAX - 1) * LDSW + xlo[j];
        oow0[j] = yr0[j] > whi;
        oow1[j] = yr1[j] > whi;
        r0[j] = yr0[j] * W_ + xlo[j];
        r1[j] = yr1[j] * W_ + xlo[j];
    }

    const int c0 = cc * CCH;
    const float* __restrict__ xb =
        x + ((size_t)n * C_ + c0) * (H_ * W_);
    float* __restrict__ ob =
        out + (((size_t)n * C_ + c0) * HO_ + ho2) * WO_ + wo;

    // Prologue: stage channel 0 into buffer 0. One global_load_lds per row per
    // wave: 64 lanes x 16B = 1024B = one W=256 f32 row; LDS dest wave-uniform,
    // linear, 16B-aligned.
    for (int r = wv; r < R; r += 4) {
        const float* gp = xb + (size_t)(wlo + r) * W_ + ln * 4;
        __builtin_amdgcn_global_load_lds(
            (const __attribute__((address_space(1))) void*)gp,
            (__attribute__((address_space(3))) void*)&sm[0][r * LDSW],
            16, 0, 0);
    }
    __syncthreads();   // vmcnt drained by barrier => rows ready

    #pragma unroll
    for (int c = 0; c < CCH; ++c) {
        // Stage next channel into the other buffer; drains at this iteration's
        // end barrier, overlapping with this channel's gather+store.
        if (c + 1 < CCH) {
            const float* xn = xb + (size_t)(c + 1) * (H_ * W_);
            for (int r = wv; r < R; r += 4) {
                const float* gp = xn + (size_t)(wlo + r) * W_ + ln * 4;
                __builtin_amdgcn_global_load_lds(
                    (const __attribute__((address_space(1))) void*)gp,
                    (__attribute__((address_space(3))) void*)&sm[(c + 1) & 1][r * LDSW],
                    16, 0, 0);
            }
        }

        const float* smb = sm[c & 1];
        const float* __restrict__ xc = xb + (size_t)c * (H_ * W_);

        #pragma unroll
        for (int j = 0; j < HB; ++j) {
            float p00 = smb[o0[j]];
            float p01 = smb[o0[j] + 1];
            float p10 = smb[o1[j]];
            float p11 = smb[o1[j] + 1];

            // Rare fallback: row fell outside the clipped window (R > RMAX).
            if (__builtin_expect(oow0[j], 0)) {
                p00 = xc[r0[j]];
                p01 = xc[r0[j] + 1];
            }
            if (__builtin_expect(oow1[j], 0)) {
                p10 = xc[r1[j]];
                p11 = xc[r1[j] + 1];
            }

            ob[(size_t)c * (HO_ * WO_) + (size_t)j * WO_] =
                p00 * W00[j] + p01 * W01[j] + p10 * W10[j] + p11 * W11[j];
        }

        if (c + 1 < CCH) __syncthreads();
    }
}

extern "C" void kernel_launch(void* const* d_in, const int* in_sizes, int n_in,
                              void* d_out, int out_size, void* d_ws, size_t ws_size,
                              hipStream_t stream) {
    const float*  x    = (const float*)d_in[0];
    const float2* grid = (const float2*)d_in[1];
    float*        out  = (float*)d_out;

    const int nblocks = N_ * NCC * (HO_ / HB);   // 8192 blocks of 256 threads
    gridsample_kernel<<<nblocks, 256, 0, stream>>>(x, grid, out);
}